// Round 1
// baseline (1213.126 us; speedup 1.0000x reference)
//
#include <hip/hip_runtime.h>
#include <math.h>

// GMFlow pipeline, fp32 correctness-first implementation.
// Shapes: B=4, C=128, H=W=64, attn_splits=2 -> 4 windows of 32x32=1024 tokens.
#define NB 4
#define NC 128
#define NH 64
#define NW 64
#define NHW 4096
#define SCALE 0.08838834764831845f  // 1/sqrt(128)

// ---------------- pos embedding table [128][32][32] ----------------
__global__ __launch_bounds__(256) void pos_kernel(float* __restrict__ pos) {
    int idx = blockIdx.x * 256 + threadIdx.x;
    if (idx >= NC * 32 * 32) return;
    int x = idx & 31;
    int y = (idx >> 5) & 31;
    int c = idx >> 10;
    const float twopi = 6.283185307179586f;
    const float denom = 32.0f + 1e-6f;
    int cc = (c < 64) ? c : (c - 64);
    float e = (c < 64) ? (float)(y + 1) : (float)(x + 1);
    e = e * (twopi / denom);
    int k = cc >> 1;
    // dim_t = 10000^(k/32) ; arg = e / dim_t = e * 2^(-k*log2(10000)/32)
    float arg = e * exp2f(-0.41524101186091903f * (float)k);
    pos[idx] = (cc & 1) ? cosf(arg) : sinf(arg);
}

// ---------------- f0p/f1p = f0/f1 + pos (per 32x32 tile) ----------------
__global__ __launch_bounds__(256) void posadd_kernel(
        const float* __restrict__ f0, const float* __restrict__ f1,
        const float* __restrict__ pos,
        float* __restrict__ f0p, float* __restrict__ f1p) {
    int i4 = blockIdx.x * 256 + threadIdx.x;
    if (i4 >= NB * NC * NHW / 4) return;
    int idx = i4 * 4;
    int hw = idx & (NHW - 1);
    int c  = (idx >> 12) & (NC - 1);
    int x = hw & 63, y = hw >> 6;
    int pidx = (c << 10) + ((y & 31) << 5) + (x & 31);
    float4 p = *reinterpret_cast<const float4*>(pos + pidx);
    float4 a = *reinterpret_cast<const float4*>(f0 + idx);
    float4 b = *reinterpret_cast<const float4*>(f1 + idx);
    a.x += p.x; a.y += p.y; a.z += p.z; a.w += p.w;
    b.x += p.x; b.y += p.y; b.z += p.z; b.w += p.w;
    *reinterpret_cast<float4*>(f0p + idx) = a;
    *reinterpret_cast<float4*>(f1p + idx) = b;
}

// ---------------- shifted-window attention (flash-style, K=V) ----------------
// block = (bn = b*4 + wi*2 + wj, rt = query row-in-window). 32 query tokens/block.
__global__ __launch_bounds__(256) void attn_kernel(
        const float* __restrict__ f0p, const float* __restrict__ f1p,
        float* __restrict__ f0a) {
    __shared__ float Qs[32][132];
    __shared__ float Ks[32][132];
    __shared__ float Ps[32][33];
    const int tid = threadIdx.x;
    const int blk = blockIdx.x;
    const int rt = blk & 31;
    const int bn = blk >> 5;
    const int b  = bn >> 2;
    const int wi = (bn >> 1) & 1;
    const int wj = bn & 1;
    const int yq = ((wi << 5) + rt + 16) & 63;   // rolled -> original row
    const float* f0b = f0p + (size_t)b * NC * NHW;
    const float* f1b = f1p + (size_t)b * NC * NHW;
    // load Q tile [32 tokens][128 ch]
    for (int idx = tid; idx < 32 * NC; idx += 256) {
        int c = idx >> 5, s = idx & 31;
        int xq = ((wj << 5) + s + 16) & 63;
        Qs[s][c] = f0b[c * NHW + yq * NW + xq];
    }
    const int sq = tid >> 3;      // query row owned in S-phase AND O-phase
    const int ug = tid & 7;
    const int cbase = ug * 16;
    // shift-window mask region of the query token (r=rt, s=sq)
    const int gq = ((wi == 0) ? 0 : ((rt < 16) ? 1 : 2)) * 3
                 + ((wj == 0) ? 0 : ((sq < 16) ? 1 : 2));
    float rm = -INFINITY, rl = 0.0f;
    float4 a0 = {0,0,0,0}, a1 = {0,0,0,0}, a2 = {0,0,0,0}, a3 = {0,0,0,0};
    for (int ut = 0; ut < 32; ++ut) {
        const int yk = ((wi << 5) + ut + 16) & 63;
        __syncthreads();  // prior iteration done with Ks/Ps
        for (int idx = tid; idx < 32 * NC; idx += 256) {
            int c = idx >> 5, su = idx & 31;
            int xk = ((wj << 5) + su + 16) & 63;
            Ks[su][c] = f1b[c * NHW + yk * NW + xk];
        }
        __syncthreads();
        const int gk_r = ((wi == 0) ? 0 : ((ut < 16) ? 1 : 2)) * 3;
        const float4* q4 = reinterpret_cast<const float4*>(&Qs[sq][0]);
        float sv[4];
        #pragma unroll
        for (int uu = 0; uu < 4; ++uu) {
            const int su = ug * 4 + uu;
            const float4* k4 = reinterpret_cast<const float4*>(&Ks[su][0]);
            float d0 = 0.f, d1 = 0.f, d2 = 0.f, d3 = 0.f;
            #pragma unroll 8
            for (int cq = 0; cq < 32; ++cq) {
                float4 q = q4[cq], k = k4[cq];
                d0 += q.x * k.x; d1 += q.y * k.y;
                d2 += q.z * k.z; d3 += q.w * k.w;
            }
            const int gk = gk_r + ((wj == 0) ? 0 : ((su < 16) ? 1 : 2));
            sv[uu] = (d0 + d1 + d2 + d3) * SCALE + ((gk != gq) ? -100.0f : 0.0f);
        }
        // row max over the 8 threads of this query row
        float tm = fmaxf(fmaxf(sv[0], sv[1]), fmaxf(sv[2], sv[3]));
        tm = fmaxf(tm, __shfl_xor(tm, 1));
        tm = fmaxf(tm, __shfl_xor(tm, 2));
        tm = fmaxf(tm, __shfl_xor(tm, 4));
        const float nm = fmaxf(rm, tm);
        const float f = expf(rm - nm);   // 0 on first iteration
        float lsum = 0.f;
        #pragma unroll
        for (int uu = 0; uu < 4; ++uu) {
            float p = expf(sv[uu] - nm);
            Ps[sq][ug * 4 + uu] = p;
            lsum += p;
        }
        lsum += __shfl_xor(lsum, 1);
        lsum += __shfl_xor(lsum, 2);
        lsum += __shfl_xor(lsum, 4);
        rl = rl * f + lsum;
        rm = nm;
        __syncthreads();  // Ps visible
        a0.x *= f; a0.y *= f; a0.z *= f; a0.w *= f;
        a1.x *= f; a1.y *= f; a1.z *= f; a1.w *= f;
        a2.x *= f; a2.y *= f; a2.z *= f; a2.w *= f;
        a3.x *= f; a3.y *= f; a3.z *= f; a3.w *= f;
        #pragma unroll 4
        for (int u = 0; u < 32; ++u) {
            const float p = Ps[sq][u];
            const float4* v4 = reinterpret_cast<const float4*>(&Ks[u][cbase]);
            float4 v0 = v4[0], v1 = v4[1], v2 = v4[2], v3 = v4[3];
            a0.x += p * v0.x; a0.y += p * v0.y; a0.z += p * v0.z; a0.w += p * v0.w;
            a1.x += p * v1.x; a1.y += p * v1.y; a1.z += p * v1.z; a1.w += p * v1.w;
            a2.x += p * v2.x; a2.y += p * v2.y; a2.z += p * v2.z; a2.w += p * v2.w;
            a3.x += p * v3.x; a3.y += p * v3.y; a3.z += p * v3.z; a3.w += p * v3.w;
        }
    }
    __syncthreads();
    const float invl = 1.0f / rl;
    float* orow = &Qs[sq][cbase];   // reuse Qs to stage output for coalesced scatter
    orow[0]  = a0.x * invl; orow[1]  = a0.y * invl; orow[2]  = a0.z * invl; orow[3]  = a0.w * invl;
    orow[4]  = a1.x * invl; orow[5]  = a1.y * invl; orow[6]  = a1.z * invl; orow[7]  = a1.w * invl;
    orow[8]  = a2.x * invl; orow[9]  = a2.y * invl; orow[10] = a2.z * invl; orow[11] = a2.w * invl;
    orow[12] = a3.x * invl; orow[13] = a3.y * invl; orow[14] = a3.z * invl; orow[15] = a3.w * invl;
    __syncthreads();
    float* f0ab = f0a + (size_t)b * NC * NHW;
    for (int idx = tid; idx < 32 * NC; idx += 256) {
        int c = idx >> 5, s = idx & 31;
        int xq = ((wj << 5) + s + 16) & 63;
        f0ab[c * NHW + yq * NW + xq] = Qs[s][c];
    }
}

// ---------------- global correlation + streaming softmax-argsoftmax ----------------
// block = (b, nt). 32 query pixels/block; stream over all 4096 source pixels.
__global__ __launch_bounds__(256) void corr_kernel(
        const float* __restrict__ f0a, const float* __restrict__ f1p,
        float* __restrict__ out) {
    __shared__ float As[32][132];
    __shared__ float Bs[32][132];
    const int tid = threadIdx.x;
    const int blk = blockIdx.x;
    const int nt = blk & 127;
    const int b  = blk >> 7;
    const float* Ab = f0a + (size_t)b * NC * NHW;
    const float* Bb = f1p + (size_t)b * NC * NHW;
    const int n0 = nt * 32;
    for (int idx = tid; idx < 32 * NC; idx += 256) {
        int c = idx >> 5, s = idx & 31;
        As[s][c] = Ab[c * NHW + n0 + s];
    }
    const int sq = tid >> 3;
    const int ug = tid & 7;
    float rm = -INFINITY, rl = 0.f, rsx = 0.f, rsy = 0.f;
    for (int mt = 0; mt < 128; ++mt) {
        const int m0 = mt * 32;
        __syncthreads();
        for (int idx = tid; idx < 32 * NC; idx += 256) {
            int c = idx >> 5, s = idx & 31;
            Bs[s][c] = Bb[c * NHW + m0 + s];
        }
        __syncthreads();
        const float4* a4 = reinterpret_cast<const float4*>(&As[sq][0]);
        float sv[4];
        #pragma unroll
        for (int uu = 0; uu < 4; ++uu) {
            const float4* b4 = reinterpret_cast<const float4*>(&Bs[ug * 4 + uu][0]);
            float d0 = 0.f, d1 = 0.f, d2 = 0.f, d3 = 0.f;
            #pragma unroll 8
            for (int cq = 0; cq < 32; ++cq) {
                float4 a = a4[cq], v = b4[cq];
                d0 += a.x * v.x; d1 += a.y * v.y;
                d2 += a.z * v.z; d3 += a.w * v.w;
            }
            sv[uu] = (d0 + d1 + d2 + d3) * SCALE;
        }
        float tm = fmaxf(fmaxf(sv[0], sv[1]), fmaxf(sv[2], sv[3]));
        tm = fmaxf(tm, __shfl_xor(tm, 1));
        tm = fmaxf(tm, __shfl_xor(tm, 2));
        tm = fmaxf(tm, __shfl_xor(tm, 4));
        const float nm = fmaxf(rm, tm);
        const float f = expf(rm - nm);
        float lsum = 0.f, lsx = 0.f;
        #pragma unroll
        for (int uu = 0; uu < 4; ++uu) {
            float p = expf(sv[uu] - nm);
            lsum += p;
            lsx += p * (float)(ug * 4 + uu);
        }
        lsum += __shfl_xor(lsum, 1);
        lsum += __shfl_xor(lsum, 2);
        lsum += __shfl_xor(lsum, 4);
        lsx += __shfl_xor(lsx, 1);
        lsx += __shfl_xor(lsx, 2);
        lsx += __shfl_xor(lsx, 4);
        const float xb = (float)(m0 & 63);
        const float yb = (float)(m0 >> 6);
        rl  = rl  * f + lsum;
        rsx = rsx * f + xb * lsum + lsx;
        rsy = rsy * f + yb * lsum;
        rm = nm;
    }
    if (ug == 0) {
        const int n = n0 + sq;
        const float xn = (float)(n & 63);
        const float yn = (float)(n >> 6);
        out[b * 2 * NHW + n]       = rsx / rl - xn;   // flow x
        out[b * 2 * NHW + NHW + n] = rsy / rl - yn;   // flow y
    }
}

extern "C" void kernel_launch(void* const* d_in, const int* in_sizes, int n_in,
                              void* d_out, int out_size, void* d_ws, size_t ws_size,
                              hipStream_t stream) {
    const float* f0 = (const float*)d_in[0];
    const float* f1 = (const float*)d_in[1];
    float* ws  = (float*)d_ws;
    float* pos = ws;                         // 131072 floats
    float* f0p = pos + 131072;               // 2097152 floats
    float* f1p = f0p + NB * NC * NHW;        // 2097152 floats
    float* f0a = f1p + NB * NC * NHW;        // 2097152 floats
    float* out = (float*)d_out;

    pos_kernel<<<512, 256, 0, stream>>>(pos);
    posadd_kernel<<<2048, 256, 0, stream>>>(f0, f1, pos, f0p, f1p);
    attn_kernel<<<512, 256, 0, stream>>>(f0p, f1p, f0a);
    corr_kernel<<<512, 256, 0, stream>>>(f0a, f1p, out);
}

// Round 2
// 425.986 us; speedup vs baseline: 2.8478x; 2.8478x over previous
//
#include <hip/hip_runtime.h>
#include <hip/hip_bf16.h>
#include <math.h>

// GMFlow pipeline. Round 2: correlation-softmax on MFMA (bf16 inputs, fp32 accum).
// Shapes: B=4, C=128, H=W=64, attn_splits=2 -> 4 windows of 32x32=1024 tokens.
#define NB 4
#define NC 128
#define NH 64
#define NW 64
#define NHW 4096
#define SCALE 0.08838834764831845f  // 1/sqrt(128)

typedef short bf16x8 __attribute__((ext_vector_type(8)));
typedef float f32x4 __attribute__((ext_vector_type(4)));

// ---------------- pos embedding table [128][32][32] ----------------
__global__ __launch_bounds__(256) void pos_kernel(float* __restrict__ pos) {
    int idx = blockIdx.x * 256 + threadIdx.x;
    if (idx >= NC * 32 * 32) return;
    int x = idx & 31;
    int y = (idx >> 5) & 31;
    int c = idx >> 10;
    const float twopi = 6.283185307179586f;
    const float denom = 32.0f + 1e-6f;
    int cc = (c < 64) ? c : (c - 64);
    float e = (c < 64) ? (float)(y + 1) : (float)(x + 1);
    e = e * (twopi / denom);
    int k = cc >> 1;
    float arg = e * exp2f(-0.41524101186091903f * (float)k);  // 10000^(-k/32)
    pos[idx] = (cc & 1) ? cosf(arg) : sinf(arg);
}

// ---------------- f0p/f1p = f0/f1 + pos (per 32x32 tile) ----------------
__global__ __launch_bounds__(256) void posadd_kernel(
        const float* __restrict__ f0, const float* __restrict__ f1,
        const float* __restrict__ pos,
        float* __restrict__ f0p, float* __restrict__ f1p) {
    int i4 = blockIdx.x * 256 + threadIdx.x;
    if (i4 >= NB * NC * NHW / 4) return;
    int idx = i4 * 4;
    int hw = idx & (NHW - 1);
    int c  = (idx >> 12) & (NC - 1);
    int x = hw & 63, y = hw >> 6;
    int pidx = (c << 10) + ((y & 31) << 5) + (x & 31);
    float4 p = *reinterpret_cast<const float4*>(pos + pidx);
    float4 a = *reinterpret_cast<const float4*>(f0 + idx);
    float4 b = *reinterpret_cast<const float4*>(f1 + idx);
    a.x += p.x; a.y += p.y; a.z += p.z; a.w += p.w;
    b.x += p.x; b.y += p.y; b.z += p.z; b.w += p.w;
    *reinterpret_cast<float4*>(f0p + idx) = a;
    *reinterpret_cast<float4*>(f1p + idx) = b;
}

// ---------------- shifted-window attention (flash-style, K=V), fp32 ----------------
__global__ __launch_bounds__(256) void attn_kernel(
        const float* __restrict__ f0p, const float* __restrict__ f1p,
        float* __restrict__ f0a) {
    __shared__ float Qs[32][132];
    __shared__ float Ks[32][132];
    __shared__ float Ps[32][33];
    const int tid = threadIdx.x;
    const int blk = blockIdx.x;
    const int rt = blk & 31;
    const int bn = blk >> 5;
    const int b  = bn >> 2;
    const int wi = (bn >> 1) & 1;
    const int wj = bn & 1;
    const int yq = ((wi << 5) + rt + 16) & 63;
    const float* f0b = f0p + (size_t)b * NC * NHW;
    const float* f1b = f1p + (size_t)b * NC * NHW;
    for (int idx = tid; idx < 32 * NC; idx += 256) {
        int c = idx >> 5, s = idx & 31;
        int xq = ((wj << 5) + s + 16) & 63;
        Qs[s][c] = f0b[c * NHW + yq * NW + xq];
    }
    const int sq = tid >> 3;
    const int ug = tid & 7;
    const int cbase = ug * 16;
    const int gq = ((wi == 0) ? 0 : ((rt < 16) ? 1 : 2)) * 3
                 + ((wj == 0) ? 0 : ((sq < 16) ? 1 : 2));
    float rm = -INFINITY, rl = 0.0f;
    float4 a0 = {0,0,0,0}, a1 = {0,0,0,0}, a2 = {0,0,0,0}, a3 = {0,0,0,0};
    for (int ut = 0; ut < 32; ++ut) {
        const int yk = ((wi << 5) + ut + 16) & 63;
        __syncthreads();
        for (int idx = tid; idx < 32 * NC; idx += 256) {
            int c = idx >> 5, su = idx & 31;
            int xk = ((wj << 5) + su + 16) & 63;
            Ks[su][c] = f1b[c * NHW + yk * NW + xk];
        }
        __syncthreads();
        const int gk_r = ((wi == 0) ? 0 : ((ut < 16) ? 1 : 2)) * 3;
        const float4* q4 = reinterpret_cast<const float4*>(&Qs[sq][0]);
        float sv[4];
        #pragma unroll
        for (int uu = 0; uu < 4; ++uu) {
            const int su = ug * 4 + uu;
            const float4* k4 = reinterpret_cast<const float4*>(&Ks[su][0]);
            float d0 = 0.f, d1 = 0.f, d2 = 0.f, d3 = 0.f;
            #pragma unroll 8
            for (int cq = 0; cq < 32; ++cq) {
                float4 q = q4[cq], k = k4[cq];
                d0 += q.x * k.x; d1 += q.y * k.y;
                d2 += q.z * k.z; d3 += q.w * k.w;
            }
            const int gk = gk_r + ((wj == 0) ? 0 : ((su < 16) ? 1 : 2));
            sv[uu] = (d0 + d1 + d2 + d3) * SCALE + ((gk != gq) ? -100.0f : 0.0f);
        }
        float tm = fmaxf(fmaxf(sv[0], sv[1]), fmaxf(sv[2], sv[3]));
        tm = fmaxf(tm, __shfl_xor(tm, 1));
        tm = fmaxf(tm, __shfl_xor(tm, 2));
        tm = fmaxf(tm, __shfl_xor(tm, 4));
        const float nm = fmaxf(rm, tm);
        const float f = expf(rm - nm);
        float lsum = 0.f;
        #pragma unroll
        for (int uu = 0; uu < 4; ++uu) {
            float p = expf(sv[uu] - nm);
            Ps[sq][ug * 4 + uu] = p;
            lsum += p;
        }
        lsum += __shfl_xor(lsum, 1);
        lsum += __shfl_xor(lsum, 2);
        lsum += __shfl_xor(lsum, 4);
        rl = rl * f + lsum;
        rm = nm;
        __syncthreads();
        a0.x *= f; a0.y *= f; a0.z *= f; a0.w *= f;
        a1.x *= f; a1.y *= f; a1.z *= f; a1.w *= f;
        a2.x *= f; a2.y *= f; a2.z *= f; a2.w *= f;
        a3.x *= f; a3.y *= f; a3.z *= f; a3.w *= f;
        #pragma unroll 4
        for (int u = 0; u < 32; ++u) {
            const float p = Ps[sq][u];
            const float4* v4 = reinterpret_cast<const float4*>(&Ks[u][cbase]);
            float4 v0 = v4[0], v1 = v4[1], v2 = v4[2], v3 = v4[3];
            a0.x += p * v0.x; a0.y += p * v0.y; a0.z += p * v0.z; a0.w += p * v0.w;
            a1.x += p * v1.x; a1.y += p * v1.y; a1.z += p * v1.z; a1.w += p * v1.w;
            a2.x += p * v2.x; a2.y += p * v2.y; a2.z += p * v2.z; a2.w += p * v2.w;
            a3.x += p * v3.x; a3.y += p * v3.y; a3.z += p * v3.z; a3.w += p * v3.w;
        }
    }
    __syncthreads();
    const float invl = 1.0f / rl;
    float* orow = &Qs[sq][cbase];
    orow[0]  = a0.x * invl; orow[1]  = a0.y * invl; orow[2]  = a0.z * invl; orow[3]  = a0.w * invl;
    orow[4]  = a1.x * invl; orow[5]  = a1.y * invl; orow[6]  = a1.z * invl; orow[7]  = a1.w * invl;
    orow[8]  = a2.x * invl; orow[9]  = a2.y * invl; orow[10] = a2.z * invl; orow[11] = a2.w * invl;
    orow[12] = a3.x * invl; orow[13] = a3.y * invl; orow[14] = a3.z * invl; orow[15] = a3.w * invl;
    __syncthreads();
    float* f0ab = f0a + (size_t)b * NC * NHW;
    for (int idx = tid; idx < 32 * NC; idx += 256) {
        int c = idx >> 5, s = idx & 31;
        int xq = ((wj << 5) + s + 16) & 63;
        f0ab[c * NHW + yq * NW + xq] = Qs[s][c];
    }
}

// ---------------- fp32 [c][n] -> bf16 [n][c] transpose (two planes) ----------------
__global__ __launch_bounds__(256) void transpose2_kernel(
        const float* __restrict__ srcA, __hip_bfloat16* __restrict__ dstA,
        const float* __restrict__ srcB, __hip_bfloat16* __restrict__ dstB) {
    __shared__ float T[64][129];
    int blk = blockIdx.x;
    const float* src = (blk < 256) ? srcA : srcB;
    __hip_bfloat16* dst = (blk < 256) ? dstA : dstB;
    blk &= 255;
    const int nt = blk & 63, b = blk >> 6;
    const float* s = src + (size_t)b * NC * NHW;
    __hip_bfloat16* d = dst + (size_t)b * NHW * NC;
    const int n0 = nt * 64;
    const int tid = threadIdx.x;
    for (int idx = tid; idx < 64 * NC; idx += 256) {
        int n = idx & 63, c = idx >> 6;
        T[n][c] = s[c * NHW + n0 + n];
    }
    __syncthreads();
    for (int idx = tid; idx < 64 * NC; idx += 256) {
        int c = idx & 127, n = idx >> 7;
        d[(size_t)(n0 + n) * NC + c] = __float2bfloat16(T[n][c]);
    }
}

// ---------------- global correlation softmax-argsoftmax on MFMA ----------------
// block = (b, nt): 64 query rows; 4 waves x 16 rows. Stream m in tiles of 64.
__global__ __launch_bounds__(256) void corr_mfma_kernel(
        const __hip_bfloat16* __restrict__ At,  // [4][4096][128]
        const __hip_bfloat16* __restrict__ Bt,  // [4][4096][128]
        float* __restrict__ out) {
    __shared__ __hip_bfloat16 Bs[2][64 * 128];  // 2 x 16 KB, double-buffered
    const int tid = threadIdx.x;
    const int lane = tid & 63;
    const int w = tid >> 6;          // wave 0..3
    const int blk = blockIdx.x;
    const int nt = blk & 63;
    const int b = blk >> 6;
    const int l15 = lane & 15;
    const int g = lane >> 4;         // 0..3
    const int n0 = nt * 64;

    const __hip_bfloat16* Ab = At + (size_t)b * NHW * NC;
    const __hip_bfloat16* Bb = Bt + (size_t)b * NHW * NC;

    // A fragments (held in registers across entire m-stream):
    // lane holds A[n = n0+w*16+l15][k = kk*32 + g*8 + j], j=0..7
    bf16x8 afrag[4];
    {
        const __hip_bfloat16* arow = Ab + (size_t)(n0 + w * 16 + l15) * NC + g * 8;
        #pragma unroll
        for (int kk = 0; kk < 4; ++kk)
            afrag[kk] = *reinterpret_cast<const bf16x8*>(arow + kk * 32);
    }

    // stage one 64x128 bf16 tile into Bs[buf] via global_load_lds.
    // LDS dest is linear (wave-uniform base + lane*16); the XOR swizzle is
    // applied to the GLOBAL source so that the swizzled ds_read below matches.
    auto stage = [&](int buf, int m0) {
        const char* srcbase = reinterpret_cast<const char*>(Bb + (size_t)m0 * NC);
        #pragma unroll
        for (int it = 0; it < 4; ++it) {
            const int obase = w * 4096 + it * 1024;
            const int o = obase + lane * 16;
            const int row = o >> 8;
            const int off = o & 255;
            const char* src = srcbase + row * 256 + (off ^ ((row & 7) << 4));
            __builtin_amdgcn_global_load_lds(
                (const __attribute__((address_space(1))) void*)src,
                (__attribute__((address_space(3))) void*)((char*)&Bs[buf][0] + obase),
                16, 0, 0);
        }
    };

    f32x4 rl = {0, 0, 0, 0}, rsx = {0, 0, 0, 0}, rsy = {0, 0, 0, 0};
    const float x0 = (float)(l15);
    const float x1 = (float)(l15 + 16);
    const float x2 = (float)(l15 + 32);
    const float x3 = (float)(l15 + 48);

    stage(0, 0);
    __syncthreads();

    for (int mt = 0; mt < 64; ++mt) {
        const int buf = mt & 1;
        if (mt < 63) stage(buf ^ 1, (mt + 1) * 64);  // prefetch next tile

        f32x4 acc[4] = {{0,0,0,0},{0,0,0,0},{0,0,0,0},{0,0,0,0}};
        const char* base = (const char*)&Bs[buf][0];
        #pragma unroll
        for (int kk = 0; kk < 4; ++kk) {
            #pragma unroll
            for (int msub = 0; msub < 4; ++msub) {
                // B[k][m]: m = msub*16 + l15 (row of Bt), k = kk*32 + g*8 + j
                const int byte = msub * 4096 + l15 * 256 +
                                 ((kk * 64 + g * 16) ^ ((l15 & 7) << 4));
                bf16x8 bfrag = *reinterpret_cast<const bf16x8*>(base + byte);
                acc[msub] = __builtin_amdgcn_mfma_f32_16x16x32_bf16(
                    afrag[kk], bfrag, acc[msub], 0, 0, 0);
            }
        }
        // streaming softmax accumulation, NO max tracking (scores*SCALE << 80,
        // exp cannot overflow fp32; -inf rows don't exist). No cross-lane ops here.
        const float y0 = (float)mt;  // y = m>>6 is constant within an aligned 64-tile
        #pragma unroll
        for (int r = 0; r < 4; ++r) {
            float p0 = __expf(acc[0][r] * SCALE);
            float p1 = __expf(acc[1][r] * SCALE);
            float p2 = __expf(acc[2][r] * SCALE);
            float p3 = __expf(acc[3][r] * SCALE);
            float ts = (p0 + p1) + (p2 + p3);
            float tx = p0 * x0 + p1 * x1 + p2 * x2 + p3 * x3;
            rl[r]  += ts;
            rsy[r] += y0 * ts;
            rsx[r] += tx;
        }
        __syncthreads();  // drains this wave's prefetch (vmcnt) + all waves done reading buf
    }

    // final reduce across the 16 lanes sharing an output row group
    #pragma unroll
    for (int r = 0; r < 4; ++r) {
        float a  = rl[r];
        float sx = rsx[r];
        float sy = rsy[r];
        #pragma unroll
        for (int m = 1; m < 16; m <<= 1) {
            a  += __shfl_xor(a, m);
            sx += __shfl_xor(sx, m);
            sy += __shfl_xor(sy, m);
        }
        if (l15 == 0) {
            const int n = n0 + w * 16 + g * 4 + r;  // D row = (lane>>4)*4 + reg
            const float xn = (float)(n & 63);
            const float yn = (float)(n >> 6);
            out[(size_t)b * 2 * NHW + n]       = sx / a - xn;
            out[(size_t)b * 2 * NHW + NHW + n] = sy / a - yn;
        }
    }
}

extern "C" void kernel_launch(void* const* d_in, const int* in_sizes, int n_in,
                              void* d_out, int out_size, void* d_ws, size_t ws_size,
                              hipStream_t stream) {
    const float* f0 = (const float*)d_in[0];
    const float* f1 = (const float*)d_in[1];
    float* ws  = (float*)d_ws;
    float* pos = ws;                         // 131072 floats
    float* f0p = pos + 131072;               // 2097152 floats (8 MB)
    float* f1p = f0p + NB * NC * NHW;        // 2097152 floats
    float* f0a = f1p + NB * NC * NHW;        // 2097152 floats
    // f0p is dead after attn -> reuse its 8 MB for the two 4 MB bf16 transposed arrays
    __hip_bfloat16* At = (__hip_bfloat16*)f0p;
    __hip_bfloat16* Bt = At + (size_t)NB * NHW * NC;
    float* out = (float*)d_out;

    pos_kernel<<<512, 256, 0, stream>>>(pos);
    posadd_kernel<<<2048, 256, 0, stream>>>(f0, f1, pos, f0p, f1p);
    attn_kernel<<<512, 256, 0, stream>>>(f0p, f1p, f0a);
    transpose2_kernel<<<512, 256, 0, stream>>>(f0a, At, f1p, Bt);
    corr_mfma_kernel<<<256, 256, 0, stream>>>(At, Bt, out);
}

// Round 3
// 95.879 us; speedup vs baseline: 12.6526x; 4.4429x over previous
//
#include <hip/hip_runtime.h>
#include <hip/hip_bf16.h>
#include <math.h>

// GMFlow pipeline. Round 3: attention AND correlation on MFMA (bf16, fp32 accum).
// B=4, C=128, H=W=64, attn_splits=2 -> 16 windows of 1024 tokens.
#define NB 4
#define NC 128
#define NH 64
#define NW 64
#define NHW 4096
#define SCALE 0.08838834764831845f  // 1/sqrt(128)

typedef short bf16x8 __attribute__((ext_vector_type(8)));
typedef float f32x4 __attribute__((ext_vector_type(4)));

__device__ __forceinline__ unsigned bfbits(float f) {
    unsigned u = __float_as_uint(f);
    return (u + 0x7FFFu + ((u >> 16) & 1u)) >> 16;   // RNE fp32->bf16
}
__device__ __forceinline__ unsigned bfpair(float a, float b) {
    return bfbits(a) | (bfbits(b) << 16);
}

// ---------------- pos embedding table [128][32][32] ----------------
__global__ __launch_bounds__(256) void pos_kernel(float* __restrict__ pos) {
    int idx = blockIdx.x * 256 + threadIdx.x;
    if (idx >= NC * 32 * 32) return;
    int x = idx & 31;
    int y = (idx >> 5) & 31;
    int c = idx >> 10;
    const float twopi = 6.283185307179586f;
    const float denom = 32.0f + 1e-6f;
    int cc = (c < 64) ? c : (c - 64);
    float e = (c < 64) ? (float)(y + 1) : (float)(x + 1);
    e = e * (twopi / denom);
    int k = cc >> 1;
    float arg = e * exp2f(-0.41524101186091903f * (float)k);  // 10000^(-k/32)
    pos[idx] = (cc & 1) ? cosf(arg) : sinf(arg);
}

// ---------------- pack: f+pos -> bf16 layouts for the MFMA kernels ----------------
// grid 512: blk<256 -> f0 -> Qw ; blk>=256 -> f1 -> Kw, Bt, Ktw
// Qw/Kw: [16 win][1024 tok][128 c]   (rolled window token order)
// Bt:    [4 b][4096 n][128 c]        (linear token order, corr B side)
// Ktw:   [16 win][128 c][1024 tok]   (transposed V for PV B-fragments)
__global__ __launch_bounds__(256) void pack_kernel(
        const float* __restrict__ f0, const float* __restrict__ f1,
        const float* __restrict__ pos,
        __hip_bfloat16* __restrict__ Qw, __hip_bfloat16* __restrict__ Kw,
        __hip_bfloat16* __restrict__ Bt, __hip_bfloat16* __restrict__ Ktw) {
    __shared__ float T[64][129];
    int blk = blockIdx.x;
    const bool isA = blk < 256;
    const float* src = isA ? f0 : f1;
    blk &= 255;
    const int y = blk & 63;
    const int b = blk >> 6;
    const int tid = threadIdx.x;
    const float* s = src + (size_t)b * NC * NHW + y * 64;
    for (int idx = tid; idx < 64 * NC; idx += 256) {
        const int x = idx & 63, c = idx >> 6;
        T[x][c] = s[c * NHW + x] + pos[(c << 10) + ((y & 31) << 5) + (x & 31)];
    }
    __syncthreads();
    const int yp = (y + 48) & 63;        // rolled row coordinate y' = (y-16) mod 64
    const int wi = yp >> 5, ry = yp & 31;
    for (int idx = tid; idx < 512; idx += 256) {
        const int x = idx >> 3, c0 = (idx & 7) * 16;
        const int xp = (x + 48) & 63;
        const int wj = xp >> 5, rx = xp & 31;
        const int win = b * 4 + wi * 2 + wj;
        const int tok = ry * 32 + rx;
        const float* tr = &T[x][c0];
        uint4 v0, v1;
        v0.x = bfpair(tr[0], tr[1]);   v0.y = bfpair(tr[2], tr[3]);
        v0.z = bfpair(tr[4], tr[5]);   v0.w = bfpair(tr[6], tr[7]);
        v1.x = bfpair(tr[8], tr[9]);   v1.y = bfpair(tr[10], tr[11]);
        v1.z = bfpair(tr[12], tr[13]); v1.w = bfpair(tr[14], tr[15]);
        __hip_bfloat16* wrow = (isA ? Qw : Kw) + ((size_t)win * 1024 + tok) * NC + c0;
        *reinterpret_cast<uint4*>(wrow) = v0;
        *reinterpret_cast<uint4*>(wrow + 8) = v1;
        if (!isA) {
            __hip_bfloat16* brow = Bt + ((size_t)b * NHW + y * 64 + x) * NC + c0;
            *reinterpret_cast<uint4*>(brow) = v0;
            *reinterpret_cast<uint4*>(brow + 8) = v1;
        }
    }
    if (!isA) {
        // Ktw: thread (c, wj) writes 32 contiguous tokens of one c-row
        const int c = tid >> 1;
        const int wj = tid & 1;
        const int win = b * 4 + wi * 2 + wj;
        unsigned up[16];
        #pragma unroll
        for (int pr = 0; pr < 16; ++pr) {
            const int x0 = ((wj << 5) + 2 * pr + 16) & 63;   // even, so x0+1 never wraps
            up[pr] = bfpair(T[x0][c], T[x0 + 1][c]);
        }
        __hip_bfloat16* krow = Ktw + ((size_t)win * NC + c) * 1024 + ry * 32;
        uint4* uv = reinterpret_cast<uint4*>(up);
        #pragma unroll
        for (int i = 0; i < 4; ++i)
            *reinterpret_cast<uint4*>(krow + i * 8) = uv[i];
    }
}

// ---------------- shifted-window attention on MFMA ----------------
// grid 256 = 16 windows x 16 q-tiles(64 rows). 4 waves x 16 q-rows.
// Swapped QK^T (mfma(K,Q)) so P^T is r<->k-adjacent; P transposed to A-layout
// through a 2KB wave-private LDS scratch. K=V; V consumed from pre-transposed Ktw.
__global__ __launch_bounds__(256) void attn_mfma_kernel(
        const __hip_bfloat16* __restrict__ Qw,
        const __hip_bfloat16* __restrict__ Kw,
        const __hip_bfloat16* __restrict__ Ktw,
        __hip_bfloat16* __restrict__ At) {
    __shared__ __align__(16) char lds[73728];
    char* KsB = lds;             // 2 x 16384 : K tile [64 m][128 c]
    char* VsB = lds + 32768;     // 2 x 16384 : Vt tile [128 c][64 m]
    char* Pscr = lds + 65536;    // 4 x 2048  : per-wave P transpose scratch
    const int tid = threadIdx.x;
    const int lane = tid & 63;
    const int w = tid >> 6;
    const int l15 = lane & 15;
    const int g = lane >> 4;
    const int blk = blockIdx.x;
    const int win = blk >> 4;
    const int qt = blk & 15;
    const int b = win >> 2, wi = (win >> 1) & 1, wj = win & 1;

    const char* Ksrc = (const char*)(Kw + (size_t)win * 1024 * NC);
    const char* Vsrc = (const char*)(Ktw + (size_t)win * NC * 1024);

    // Q fragments: lane holds Q[q = qt*64+w*16+l15][c = kk*32+g*8+j]
    bf16x8 qf[4];
    {
        const __hip_bfloat16* qrow =
            Qw + ((size_t)win * 1024 + qt * 64 + w * 16 + l15) * NC + g * 8;
        #pragma unroll
        for (int kk = 0; kk < 4; ++kk)
            qf[kk] = *reinterpret_cast<const bf16x8*>(qrow + kk * 32);
    }

    // shift-window mask regions: all boundaries 16-aligned =>
    // region(q) wave-uniform, region(k) depends only on (kt, msub)
    const int reg_q = (wi ? (qt < 8 ? 1 : 2) : 0) * 3
                    + (wj ? ((w & 1) == 0 ? 1 : 2) : 0);

    auto stageK = [&](int buf, int kt) {
        const char* sb = Ksrc + (size_t)kt * 64 * 256;
        char* dst = KsB + buf * 16384;
        #pragma unroll
        for (int it = 0; it < 4; ++it) {
            const int obase = w * 4096 + it * 1024;
            const int o = obase + lane * 16;
            const int row = o >> 8;
            const int off = o & 255;
            __builtin_amdgcn_global_load_lds(
                (const __attribute__((address_space(1))) void*)(sb + row * 256 + (off ^ ((row & 7) << 4))),
                (__attribute__((address_space(3))) void*)(dst + obase), 16, 0, 0);
        }
    };
    auto stageV = [&](int buf, int kt) {
        char* dst = VsB + buf * 16384;
        #pragma unroll
        for (int it = 0; it < 4; ++it) {
            const int obase = w * 4096 + it * 1024;
            const int o = obase + lane * 16;
            const int crow = o >> 7;
            const int off = o & 127;
            __builtin_amdgcn_global_load_lds(
                (const __attribute__((address_space(1))) void*)(Vsrc + crow * 2048 + kt * 128 + (off ^ ((crow & 7) << 4))),
                (__attribute__((address_space(3))) void*)(dst + obase), 16, 0, 0);
        }
    };

    f32x4 oacc[8] = {{0,0,0,0},{0,0,0,0},{0,0,0,0},{0,0,0,0},
                     {0,0,0,0},{0,0,0,0},{0,0,0,0},{0,0,0,0}};
    float zacc = 0.f;

    stageK(0, 0); stageV(0, 0);
    __syncthreads();

    for (int kt = 0; kt < 16; ++kt) {
        const int buf = kt & 1;
        if (kt < 15) { stageK(buf ^ 1, kt + 1); stageV(buf ^ 1, kt + 1); }

        // S^T[k][q] = K . Q^T : A = K-frag (rows k), B = Q-frag (cols q)
        const char* kb = KsB + buf * 16384;
        f32x4 sacc[4] = {{0,0,0,0},{0,0,0,0},{0,0,0,0},{0,0,0,0}};
        #pragma unroll
        for (int kk = 0; kk < 4; ++kk) {
            #pragma unroll
            for (int msub = 0; msub < 4; ++msub) {
                const int byte = msub * 4096 + l15 * 256 + ((kk * 64 + g * 16) ^ ((l15 & 7) << 4));
                bf16x8 kf = *reinterpret_cast<const bf16x8*>(kb + byte);
                sacc[msub] = __builtin_amdgcn_mfma_f32_16x16x32_bf16(kf, qf[kk], sacc[msub], 0, 0, 0);
            }
        }

        // mask + exp (no max needed: |s*SCALE| small) + Z + pack P^T -> A-layout
        const int rk_row = (wi ? (kt < 8 ? 1 : 2) : 0) * 3;
        char* pw = Pscr + w * 2048;
        #pragma unroll
        for (int msub = 0; msub < 4; ++msub) {
            const int rk = rk_row + (wj ? ((msub & 1) == 0 ? 1 : 2) : 0);
            const bool ok = (rk == reg_q);
            const float p0 = ok ? __expf(sacc[msub][0] * SCALE) : 0.f;
            const float p1 = ok ? __expf(sacc[msub][1] * SCALE) : 0.f;
            const float p2 = ok ? __expf(sacc[msub][2] * SCALE) : 0.f;
            const float p3 = ok ? __expf(sacc[msub][3] * SCALE) : 0.f;
            zacc += (p0 + p1) + (p2 + p3);
            *reinterpret_cast<unsigned*>(pw + l15 * 128 + ((msub * 32 + g * 8 + 0) ^ ((l15 & 7) << 4))) = bfpair(p0, p1);
            *reinterpret_cast<unsigned*>(pw + l15 * 128 + ((msub * 32 + g * 8 + 4) ^ ((l15 & 7) << 4))) = bfpair(p2, p3);
        }
        // read P as A-fragments: lane holds P[q = l15][k = kk*32+g*8+j]
        bf16x8 pf[2];
        #pragma unroll
        for (int kk = 0; kk < 2; ++kk)
            pf[kk] = *reinterpret_cast<const bf16x8*>(pw + l15 * 128 + ((kk * 64 + g * 16) ^ ((l15 & 7) << 4)));

        // O[q][c] += P . V
        const char* vb = VsB + buf * 16384;
        #pragma unroll
        for (int kk = 0; kk < 2; ++kk) {
            #pragma unroll
            for (int co = 0; co < 8; ++co) {
                const int byte = (co * 16 + l15) * 128 + ((kk * 64 + g * 16) ^ ((l15 & 7) << 4));
                bf16x8 vf = *reinterpret_cast<const bf16x8*>(vb + byte);
                oacc[co] = __builtin_amdgcn_mfma_f32_16x16x32_bf16(pf[kk], vf, oacc[co], 0, 0, 0);
            }
        }
        __syncthreads();
    }

    // Z: reduce the k-partition across the 4 g-groups (q = l15 per lane)
    float z = zacc;
    z += __shfl_xor(z, 16);
    z += __shfl_xor(z, 32);

    // normalize + stage O[16 q][128 c] bf16 in per-wave LDS (reuse Ks area)
    unsigned short* olds = reinterpret_cast<unsigned short*>(lds + w * 4096);
    #pragma unroll
    for (int r = 0; r < 4; ++r) {
        const float zi = 1.0f / __shfl(z, g * 4 + r);
        #pragma unroll
        for (int co = 0; co < 8; ++co)
            olds[(g * 4 + r) * 128 + co * 16 + l15] = (unsigned short)bfbits(oacc[co][r] * zi);
    }

    // coalesced copy to At with window -> original-coordinate mapping
    const int qloc = lane >> 2;
    const int c0 = (lane & 3) * 32;
    const int tok = qt * 64 + w * 16 + qloc;
    const int yo = ((wi << 5) + (tok >> 5) + 16) & 63;
    const int xo = ((wj << 5) + (tok & 31) + 16) & 63;
    __hip_bfloat16* arow = At + ((size_t)b * NHW + yo * 64 + xo) * NC + c0;
    #pragma unroll
    for (int i = 0; i < 4; ++i) {
        int4 v = *reinterpret_cast<const int4*>(olds + qloc * 128 + c0 + i * 8);
        *reinterpret_cast<int4*>(arow + i * 8) = v;
    }
}

// ---------------- global correlation softmax-argsoftmax on MFMA ----------------
__global__ __launch_bounds__(256) void corr_mfma_kernel(
        const __hip_bfloat16* __restrict__ At,  // [4][4096][128]
        const __hip_bfloat16* __restrict__ Bt,  // [4][4096][128]
        float* __restrict__ out) {
    __shared__ __hip_bfloat16 Bs[2][64 * 128];
    const int tid = threadIdx.x;
    const int lane = tid & 63;
    const int w = tid >> 6;
    const int blk = blockIdx.x;
    const int nt = blk & 63;
    const int b = blk >> 6;
    const int l15 = lane & 15;
    const int g = lane >> 4;
    const int n0 = nt * 64;

    const __hip_bfloat16* Ab = At + (size_t)b * NHW * NC;
    const __hip_bfloat16* Bb = Bt + (size_t)b * NHW * NC;

    bf16x8 afrag[4];
    {
        const __hip_bfloat16* arow = Ab + (size_t)(n0 + w * 16 + l15) * NC + g * 8;
        #pragma unroll
        for (int kk = 0; kk < 4; ++kk)
            afrag[kk] = *reinterpret_cast<const bf16x8*>(arow + kk * 32);
    }

    auto stage = [&](int buf, int m0) {
        const char* srcbase = reinterpret_cast<const char*>(Bb + (size_t)m0 * NC);
        #pragma unroll
        for (int it = 0; it < 4; ++it) {
            const int obase = w * 4096 + it * 1024;
            const int o = obase + lane * 16;
            const int row = o >> 8;
            const int off = o & 255;
            const char* src = srcbase + row * 256 + (off ^ ((row & 7) << 4));
            __builtin_amdgcn_global_load_lds(
                (const __attribute__((address_space(1))) void*)src,
                (__attribute__((address_space(3))) void*)((char*)&Bs[buf][0] + obase),
                16, 0, 0);
        }
    };

    f32x4 rl = {0, 0, 0, 0}, rsx = {0, 0, 0, 0}, rsy = {0, 0, 0, 0};
    const float x0 = (float)(l15);
    const float x1 = (float)(l15 + 16);
    const float x2 = (float)(l15 + 32);
    const float x3 = (float)(l15 + 48);

    stage(0, 0);
    __syncthreads();

    for (int mt = 0; mt < 64; ++mt) {
        const int buf = mt & 1;
        if (mt < 63) stage(buf ^ 1, (mt + 1) * 64);

        f32x4 acc[4] = {{0,0,0,0},{0,0,0,0},{0,0,0,0},{0,0,0,0}};
        const char* base = (const char*)&Bs[buf][0];
        #pragma unroll
        for (int kk = 0; kk < 4; ++kk) {
            #pragma unroll
            for (int msub = 0; msub < 4; ++msub) {
                const int byte = msub * 4096 + l15 * 256 +
                                 ((kk * 64 + g * 16) ^ ((l15 & 7) << 4));
                bf16x8 bfrag = *reinterpret_cast<const bf16x8*>(base + byte);
                acc[msub] = __builtin_amdgcn_mfma_f32_16x16x32_bf16(
                    afrag[kk], bfrag, acc[msub], 0, 0, 0);
            }
        }
        const float y0 = (float)mt;
        #pragma unroll
        for (int r = 0; r < 4; ++r) {
            float p0 = __expf(acc[0][r] * SCALE);
            float p1 = __expf(acc[1][r] * SCALE);
            float p2 = __expf(acc[2][r] * SCALE);
            float p3 = __expf(acc[3][r] * SCALE);
            float ts = (p0 + p1) + (p2 + p3);
            float tx = p0 * x0 + p1 * x1 + p2 * x2 + p3 * x3;
            rl[r]  += ts;
            rsy[r] += y0 * ts;
            rsx[r] += tx;
        }
        __syncthreads();
    }

    #pragma unroll
    for (int r = 0; r < 4; ++r) {
        float a  = rl[r];
        float sx = rsx[r];
        float sy = rsy[r];
        #pragma unroll
        for (int m = 1; m < 16; m <<= 1) {
            a  += __shfl_xor(a, m);
            sx += __shfl_xor(sx, m);
            sy += __shfl_xor(sy, m);
        }
        if (l15 == 0) {
            const int n = n0 + w * 16 + g * 4 + r;
            const float xn = (float)(n & 63);
            const float yn = (float)(n >> 6);
            out[(size_t)b * 2 * NHW + n]       = sx / a - xn;
            out[(size_t)b * 2 * NHW + NHW + n] = sy / a - yn;
        }
    }
}

extern "C" void kernel_launch(void* const* d_in, const int* in_sizes, int n_in,
                              void* d_out, int out_size, void* d_ws, size_t ws_size,
                              hipStream_t stream) {
    const float* f0 = (const float*)d_in[0];
    const float* f1 = (const float*)d_in[1];
    float* ws  = (float*)d_ws;
    float* pos = ws;                                     // 131072 f32 (512 KB)
    __hip_bfloat16* Qw  = (__hip_bfloat16*)(pos + 131072);   // 16*1024*128 (4 MB)
    __hip_bfloat16* Kw  = Qw  + (size_t)16 * 1024 * NC;      // 4 MB
    __hip_bfloat16* Bt  = Kw  + (size_t)16 * 1024 * NC;      // 4 MB
    __hip_bfloat16* Ktw = Bt  + (size_t)NB * NHW * NC;       // 4 MB
    __hip_bfloat16* At  = Ktw + (size_t)16 * NC * 1024;      // 4 MB
    float* out = (float*)d_out;

    pos_kernel<<<512, 256, 0, stream>>>(pos);
    pack_kernel<<<512, 256, 0, stream>>>(f0, f1, pos, Qw, Kw, Bt, Ktw);
    attn_mfma_kernel<<<256, 256, 0, stream>>>(Qw, Kw, Ktw, At);
    corr_mfma_kernel<<<256, 256, 0, stream>>>(At, Bt, out);
}

// Round 4
// 70.124 us; speedup vs baseline: 17.2998x; 1.3673x over previous
//
#include <hip/hip_runtime.h>
#include <hip/hip_bf16.h>
#include <math.h>

// GMFlow pipeline. Round 4: corr m-split 4x for occupancy (linear partials),
// SCALE folded into packed Q and attn output.
#define NB 4
#define NC 128
#define NH 64
#define NW 64
#define NHW 4096
#define SCALE 0.08838834764831845f  // 1/sqrt(128)

typedef short bf16x8 __attribute__((ext_vector_type(8)));
typedef float f32x4 __attribute__((ext_vector_type(4)));

__device__ __forceinline__ unsigned bfbits(float f) {
    unsigned u = __float_as_uint(f);
    return (u + 0x7FFFu + ((u >> 16) & 1u)) >> 16;   // RNE fp32->bf16
}
__device__ __forceinline__ unsigned bfpair(float a, float b) {
    return bfbits(a) | (bfbits(b) << 16);
}

// ---------------- pos embedding table [128][32][32] ----------------
__global__ __launch_bounds__(256) void pos_kernel(float* __restrict__ pos) {
    int idx = blockIdx.x * 256 + threadIdx.x;
    if (idx >= NC * 32 * 32) return;
    int x = idx & 31;
    int y = (idx >> 5) & 31;
    int c = idx >> 10;
    const float twopi = 6.283185307179586f;
    const float denom = 32.0f + 1e-6f;
    int cc = (c < 64) ? c : (c - 64);
    float e = (c < 64) ? (float)(y + 1) : (float)(x + 1);
    e = e * (twopi / denom);
    int k = cc >> 1;
    float arg = e * exp2f(-0.41524101186091903f * (float)k);  // 10000^(-k/32)
    pos[idx] = (cc & 1) ? cosf(arg) : sinf(arg);
}

// ---------------- pack: f+pos -> bf16 layouts for the MFMA kernels ----------------
// grid 512: blk<256 -> f0 -> Qw (pre-scaled by SCALE) ; blk>=256 -> f1 -> Kw, Bt, Ktw
__global__ __launch_bounds__(256) void pack_kernel(
        const float* __restrict__ f0, const float* __restrict__ f1,
        const float* __restrict__ pos,
        __hip_bfloat16* __restrict__ Qw, __hip_bfloat16* __restrict__ Kw,
        __hip_bfloat16* __restrict__ Bt, __hip_bfloat16* __restrict__ Ktw) {
    __shared__ float T[64][129];
    int blk = blockIdx.x;
    const bool isA = blk < 256;
    const float* src = isA ? f0 : f1;
    blk &= 255;
    const int y = blk & 63;
    const int b = blk >> 6;
    const int tid = threadIdx.x;
    const float* s = src + (size_t)b * NC * NHW + y * 64;
    for (int idx = tid; idx < 64 * NC; idx += 256) {
        const int x = idx & 63, c = idx >> 6;
        T[x][c] = s[c * NHW + x] + pos[(c << 10) + ((y & 31) << 5) + (x & 31)];
    }
    __syncthreads();
    const float sA = isA ? SCALE : 1.0f;   // fold QK^T scale into Q
    const int yp = (y + 48) & 63;          // rolled row y' = (y-16) mod 64
    const int wi = yp >> 5, ry = yp & 31;
    for (int idx = tid; idx < 512; idx += 256) {
        const int x = idx >> 3, c0 = (idx & 7) * 16;
        const int xp = (x + 48) & 63;
        const int wj = xp >> 5, rx = xp & 31;
        const int win = b * 4 + wi * 2 + wj;
        const int tok = ry * 32 + rx;
        const float* tr = &T[x][c0];
        uint4 v0, v1;
        v0.x = bfpair(tr[0] * sA, tr[1] * sA);   v0.y = bfpair(tr[2] * sA, tr[3] * sA);
        v0.z = bfpair(tr[4] * sA, tr[5] * sA);   v0.w = bfpair(tr[6] * sA, tr[7] * sA);
        v1.x = bfpair(tr[8] * sA, tr[9] * sA);   v1.y = bfpair(tr[10] * sA, tr[11] * sA);
        v1.z = bfpair(tr[12] * sA, tr[13] * sA); v1.w = bfpair(tr[14] * sA, tr[15] * sA);
        __hip_bfloat16* wrow = (isA ? Qw : Kw) + ((size_t)win * 1024 + tok) * NC + c0;
        *reinterpret_cast<uint4*>(wrow) = v0;
        *reinterpret_cast<uint4*>(wrow + 8) = v1;
        if (!isA) {
            __hip_bfloat16* brow = Bt + ((size_t)b * NHW + y * 64 + x) * NC + c0;
            *reinterpret_cast<uint4*>(brow) = v0;
            *reinterpret_cast<uint4*>(brow + 8) = v1;
        }
    }
    if (!isA) {
        const int c = tid >> 1;
        const int wj = tid & 1;
        const int win = b * 4 + wi * 2 + wj;
        unsigned up[16];
        #pragma unroll
        for (int pr = 0; pr < 16; ++pr) {
            const int x0 = ((wj << 5) + 2 * pr + 16) & 63;
            up[pr] = bfpair(T[x0][c], T[x0 + 1][c]);
        }
        __hip_bfloat16* krow = Ktw + ((size_t)win * NC + c) * 1024 + ry * 32;
        uint4* uv = reinterpret_cast<uint4*>(up);
        #pragma unroll
        for (int i = 0; i < 4; ++i)
            *reinterpret_cast<uint4*>(krow + i * 8) = uv[i];
    }
}

// ---------------- shifted-window attention on MFMA ----------------
// grid 256 = 16 windows x 16 q-tiles(64 rows). Output At pre-scaled by SCALE.
__global__ __launch_bounds__(256) void attn_mfma_kernel(
        const __hip_bfloat16* __restrict__ Qw,
        const __hip_bfloat16* __restrict__ Kw,
        const __hip_bfloat16* __restrict__ Ktw,
        __hip_bfloat16* __restrict__ At) {
    __shared__ __align__(16) char lds[73728];
    char* KsB = lds;             // 2 x 16384 : K tile [64 m][128 c]
    char* VsB = lds + 32768;     // 2 x 16384 : Vt tile [128 c][64 m]
    char* Pscr = lds + 65536;    // 4 x 2048  : per-wave P transpose scratch
    const int tid = threadIdx.x;
    const int lane = tid & 63;
    const int w = tid >> 6;
    const int l15 = lane & 15;
    const int g = lane >> 4;
    const int blk = blockIdx.x;
    const int win = blk >> 4;
    const int qt = blk & 15;
    const int b = win >> 2, wi = (win >> 1) & 1, wj = win & 1;

    const char* Ksrc = (const char*)(Kw + (size_t)win * 1024 * NC);
    const char* Vsrc = (const char*)(Ktw + (size_t)win * NC * 1024);

    bf16x8 qf[4];
    {
        const __hip_bfloat16* qrow =
            Qw + ((size_t)win * 1024 + qt * 64 + w * 16 + l15) * NC + g * 8;
        #pragma unroll
        for (int kk = 0; kk < 4; ++kk)
            qf[kk] = *reinterpret_cast<const bf16x8*>(qrow + kk * 32);
    }

    const int reg_q = (wi ? (qt < 8 ? 1 : 2) : 0) * 3
                    + (wj ? ((w & 1) == 0 ? 1 : 2) : 0);

    auto stageK = [&](int buf, int kt) {
        const char* sb = Ksrc + (size_t)kt * 64 * 256;
        char* dst = KsB + buf * 16384;
        #pragma unroll
        for (int it = 0; it < 4; ++it) {
            const int obase = w * 4096 + it * 1024;
            const int o = obase + lane * 16;
            const int row = o >> 8;
            const int off = o & 255;
            __builtin_amdgcn_global_load_lds(
                (const __attribute__((address_space(1))) void*)(sb + row * 256 + (off ^ ((row & 7) << 4))),
                (__attribute__((address_space(3))) void*)(dst + obase), 16, 0, 0);
        }
    };
    auto stageV = [&](int buf, int kt) {
        char* dst = VsB + buf * 16384;
        #pragma unroll
        for (int it = 0; it < 4; ++it) {
            const int obase = w * 4096 + it * 1024;
            const int o = obase + lane * 16;
            const int crow = o >> 7;
            const int off = o & 127;
            __builtin_amdgcn_global_load_lds(
                (const __attribute__((address_space(1))) void*)(Vsrc + crow * 2048 + kt * 128 + (off ^ ((crow & 7) << 4))),
                (__attribute__((address_space(3))) void*)(dst + obase), 16, 0, 0);
        }
    };

    f32x4 oacc[8] = {{0,0,0,0},{0,0,0,0},{0,0,0,0},{0,0,0,0},
                     {0,0,0,0},{0,0,0,0},{0,0,0,0},{0,0,0,0}};
    float zacc = 0.f;

    stageK(0, 0); stageV(0, 0);
    __syncthreads();

    for (int kt = 0; kt < 16; ++kt) {
        const int buf = kt & 1;
        if (kt < 15) { stageK(buf ^ 1, kt + 1); stageV(buf ^ 1, kt + 1); }

        const char* kb = KsB + buf * 16384;
        f32x4 sacc[4] = {{0,0,0,0},{0,0,0,0},{0,0,0,0},{0,0,0,0}};
        #pragma unroll
        for (int kk = 0; kk < 4; ++kk) {
            #pragma unroll
            for (int msub = 0; msub < 4; ++msub) {
                const int byte = msub * 4096 + l15 * 256 + ((kk * 64 + g * 16) ^ ((l15 & 7) << 4));
                bf16x8 kf = *reinterpret_cast<const bf16x8*>(kb + byte);
                sacc[msub] = __builtin_amdgcn_mfma_f32_16x16x32_bf16(kf, qf[kk], sacc[msub], 0, 0, 0);
            }
        }

        const int rk_row = (wi ? (kt < 8 ? 1 : 2) : 0) * 3;
        char* pw = Pscr + w * 2048;
        #pragma unroll
        for (int msub = 0; msub < 4; ++msub) {
            const int rk = rk_row + (wj ? ((msub & 1) == 0 ? 1 : 2) : 0);
            const bool ok = (rk == reg_q);
            const float p0 = ok ? __expf(sacc[msub][0]) : 0.f;   // Q pre-scaled
            const float p1 = ok ? __expf(sacc[msub][1]) : 0.f;
            const float p2 = ok ? __expf(sacc[msub][2]) : 0.f;
            const float p3 = ok ? __expf(sacc[msub][3]) : 0.f;
            zacc += (p0 + p1) + (p2 + p3);
            *reinterpret_cast<unsigned*>(pw + l15 * 128 + ((msub * 32 + g * 8 + 0) ^ ((l15 & 7) << 4))) = bfpair(p0, p1);
            *reinterpret_cast<unsigned*>(pw + l15 * 128 + ((msub * 32 + g * 8 + 4) ^ ((l15 & 7) << 4))) = bfpair(p2, p3);
        }
        bf16x8 pf[2];
        #pragma unroll
        for (int kk = 0; kk < 2; ++kk)
            pf[kk] = *reinterpret_cast<const bf16x8*>(pw + l15 * 128 + ((kk * 64 + g * 16) ^ ((l15 & 7) << 4)));

        const char* vb = VsB + buf * 16384;
        #pragma unroll
        for (int kk = 0; kk < 2; ++kk) {
            #pragma unroll
            for (int co = 0; co < 8; ++co) {
                const int byte = (co * 16 + l15) * 128 + ((kk * 64 + g * 16) ^ ((l15 & 7) << 4));
                bf16x8 vf = *reinterpret_cast<const bf16x8*>(vb + byte);
                oacc[co] = __builtin_amdgcn_mfma_f32_16x16x32_bf16(pf[kk], vf, oacc[co], 0, 0, 0);
            }
        }
        __syncthreads();
    }

    float z = zacc;
    z += __shfl_xor(z, 16);
    z += __shfl_xor(z, 32);

    // normalize (and pre-scale by SCALE for the downstream correlation)
    unsigned short* olds = reinterpret_cast<unsigned short*>(lds + w * 4096);
    #pragma unroll
    for (int r = 0; r < 4; ++r) {
        const float zi = SCALE / __shfl(z, g * 4 + r);
        #pragma unroll
        for (int co = 0; co < 8; ++co)
            olds[(g * 4 + r) * 128 + co * 16 + l15] = (unsigned short)bfbits(oacc[co][r] * zi);
    }

    const int qloc = lane >> 2;
    const int c0 = (lane & 3) * 32;
    const int tok = qt * 64 + w * 16 + qloc;
    const int yo = ((wi << 5) + (tok >> 5) + 16) & 63;
    const int xo = ((wj << 5) + (tok & 31) + 16) & 63;
    __hip_bfloat16* arow = At + ((size_t)b * NHW + yo * 64 + xo) * NC + c0;
    #pragma unroll
    for (int i = 0; i < 4; ++i) {
        int4 v = *reinterpret_cast<const int4*>(olds + qloc * 128 + c0 + i * 8);
        *reinterpret_cast<int4*>(arow + i * 8) = v;
    }
}

// ---------------- correlation partials: m-split x4 ----------------
// grid 1024 = 4 b x 64 nt x 4 ms. Each block: 64 q-rows, 16 m-tiles (of 64).
// Emits per-row partial (sum p, sum p*x, sum p*y) -- linear, no max tracking.
__global__ __launch_bounds__(256) void corr_part_kernel(
        const __hip_bfloat16* __restrict__ At,  // [4][4096][128], pre-scaled
        const __hip_bfloat16* __restrict__ Bt,  // [4][4096][128]
        float4* __restrict__ part) {            // [4][4096][4 ms]
    __shared__ __hip_bfloat16 Bs[2][64 * 128];
    const int tid = threadIdx.x;
    const int lane = tid & 63;
    const int w = tid >> 6;
    const int blk = blockIdx.x;
    const int ms = blk & 3;
    const int nt = (blk >> 2) & 63;
    const int b = blk >> 8;
    const int l15 = lane & 15;
    const int g = lane >> 4;
    const int n0 = nt * 64;

    const __hip_bfloat16* Ab = At + (size_t)b * NHW * NC;
    const __hip_bfloat16* Bb = Bt + (size_t)b * NHW * NC;

    bf16x8 afrag[4];
    {
        const __hip_bfloat16* arow = Ab + (size_t)(n0 + w * 16 + l15) * NC + g * 8;
        #pragma unroll
        for (int kk = 0; kk < 4; ++kk)
            afrag[kk] = *reinterpret_cast<const bf16x8*>(arow + kk * 32);
    }

    auto stage = [&](int buf, int mtile) {
        const char* srcbase = reinterpret_cast<const char*>(Bb + (size_t)mtile * 64 * NC);
        #pragma unroll
        for (int it = 0; it < 4; ++it) {
            const int obase = w * 4096 + it * 1024;
            const int o = obase + lane * 16;
            const int row = o >> 8;
            const int off = o & 255;
            const char* src = srcbase + row * 256 + (off ^ ((row & 7) << 4));
            __builtin_amdgcn_global_load_lds(
                (const __attribute__((address_space(1))) void*)src,
                (__attribute__((address_space(3))) void*)((char*)&Bs[buf][0] + obase),
                16, 0, 0);
        }
    };

    f32x4 rl = {0, 0, 0, 0}, rsm = {0, 0, 0, 0}, rsy = {0, 0, 0, 0};

    stage(0, ms * 16);
    __syncthreads();

    for (int mt = 0; mt < 16; ++mt) {
        const int buf = mt & 1;
        if (mt < 15) stage(buf ^ 1, ms * 16 + mt + 1);

        f32x4 acc[4] = {{0,0,0,0},{0,0,0,0},{0,0,0,0},{0,0,0,0}};
        const char* base = (const char*)&Bs[buf][0];
        #pragma unroll
        for (int kk = 0; kk < 4; ++kk) {
            #pragma unroll
            for (int msub = 0; msub < 4; ++msub) {
                const int byte = msub * 4096 + l15 * 256 +
                                 ((kk * 64 + g * 16) ^ ((l15 & 7) << 4));
                bf16x8 bfrag = *reinterpret_cast<const bf16x8*>(base + byte);
                acc[msub] = __builtin_amdgcn_mfma_f32_16x16x32_bf16(
                    afrag[kk], bfrag, acc[msub], 0, 0, 0);
            }
        }
        const float y0 = (float)(ms * 16 + mt);   // m>>6 constant per aligned tile
        #pragma unroll
        for (int r = 0; r < 4; ++r) {
            float p0 = __expf(acc[0][r]);   // A pre-scaled by SCALE
            float p1 = __expf(acc[1][r]);
            float p2 = __expf(acc[2][r]);
            float p3 = __expf(acc[3][r]);
            float ts = (p0 + p1) + (p2 + p3);
            rl[r]  += ts;
            rsy[r] += y0 * ts;
            rsm[r] += fmaf(3.f, p3, fmaf(2.f, p2, p1));  // x = l15 + 16*msub
        }
        __syncthreads();
    }

    const float xl = (float)l15;
    #pragma unroll
    for (int r = 0; r < 4; ++r) {
        float a  = rl[r];
        float sx = xl * rl[r] + 16.f * rsm[r];
        float sy = rsy[r];
        #pragma unroll
        for (int m = 1; m < 16; m <<= 1) {
            a  += __shfl_xor(a, m);
            sx += __shfl_xor(sx, m);
            sy += __shfl_xor(sy, m);
        }
        if (l15 == 0) {
            const int n = n0 + w * 16 + g * 4 + r;
            part[((size_t)b * NHW + n) * 4 + ms] = make_float4(a, sx, sy, 0.f);
        }
    }
}

// ---------------- finalize: combine 4 partials, emit flow ----------------
__global__ __launch_bounds__(256) void finalize_kernel(
        const float4* __restrict__ part, float* __restrict__ out) {
    const int idx = blockIdx.x * 256 + threadIdx.x;   // 0..16383 = b*4096+n
    if (idx >= NB * NHW) return;
    const int n = idx & (NHW - 1);
    const int b = idx >> 12;
    float4 p0 = part[(size_t)idx * 4 + 0];
    float4 p1 = part[(size_t)idx * 4 + 1];
    float4 p2 = part[(size_t)idx * 4 + 2];
    float4 p3 = part[(size_t)idx * 4 + 3];
    const float l  = (p0.x + p1.x) + (p2.x + p3.x);
    const float sx = (p0.y + p1.y) + (p2.y + p3.y);
    const float sy = (p0.z + p1.z) + (p2.z + p3.z);
    const float inv = 1.0f / l;
    out[(size_t)b * 2 * NHW + n]       = sx * inv - (float)(n & 63);
    out[(size_t)b * 2 * NHW + NHW + n] = sy * inv - (float)(n >> 6);
}

extern "C" void kernel_launch(void* const* d_in, const int* in_sizes, int n_in,
                              void* d_out, int out_size, void* d_ws, size_t ws_size,
                              hipStream_t stream) {
    const float* f0 = (const float*)d_in[0];
    const float* f1 = (const float*)d_in[1];
    float* ws  = (float*)d_ws;
    float* pos = ws;                                     // 512 KB
    __hip_bfloat16* Qw  = (__hip_bfloat16*)(pos + 131072);   // 4 MB
    __hip_bfloat16* Kw  = Qw  + (size_t)16 * 1024 * NC;      // 4 MB
    __hip_bfloat16* Bt  = Kw  + (size_t)16 * 1024 * NC;      // 4 MB
    __hip_bfloat16* Ktw = Bt  + (size_t)NB * NHW * NC;       // 4 MB
    __hip_bfloat16* At  = Ktw + (size_t)16 * NC * 1024;      // 4 MB
    float4* part = (float4*)(At + (size_t)NB * NHW * NC);    // 1 MB
    float* out = (float*)d_out;

    pos_kernel<<<512, 256, 0, stream>>>(pos);
    pack_kernel<<<512, 256, 0, stream>>>(f0, f1, pos, Qw, Kw, Bt, Ktw);
    attn_mfma_kernel<<<256, 256, 0, stream>>>(Qw, Kw, Ktw, At);
    corr_part_kernel<<<1024, 256, 0, stream>>>(At, Bt, part);
    finalize_kernel<<<64, 256, 0, stream>>>(part, out);
}